// Round 1
// baseline (14.522 us; speedup 1.0000x reference)
//
#include <hip/hip_runtime.h>
#include <math.h>

#define IMGS 28
#define NPSD 14
#define NPAT 196
#define NCLS 10
#define NFEAT (NPAT * 3)

// ---- 4-qubit gate helpers: all indices compile-time (templates + unroll) ----

template <int MASK>
__device__ __forceinline__ void ry_gate(float (&sr)[16], float (&si)[16], float c, float s) {
#pragma unroll
    for (int i = 0; i < 16; ++i) {
        if (i & MASK) continue;
        const int j = i | MASK;
        float r0 = sr[i], q0 = si[i], r1 = sr[j], q1 = si[j];
        sr[i] = c * r0 - s * r1;  si[i] = c * q0 - s * q1;
        sr[j] = s * r0 + c * r1;  si[j] = s * q0 + c * q1;
    }
}

template <int MC, int MT>
__device__ __forceinline__ void cx_gate(float (&sr)[16], float (&si)[16]) {
#pragma unroll
    for (int i = 0; i < 16; ++i) {
        if ((i & MC) && !(i & MT)) {
            const int j = i | MT;
            float tr = sr[i], ti = si[i];
            sr[i] = sr[j]; si[i] = si[j];
            sr[j] = tr;    si[j] = ti;
        }
    }
}

template <int MC, int MT>
__device__ __forceinline__ void crx_gate(float (&sr)[16], float (&si)[16], float c, float s) {
#pragma unroll
    for (int i = 0; i < 16; ++i) {
        if ((i & MC) && !(i & MT)) {
            const int j = i | MT;
            float r0 = sr[i], q0 = si[i], r1 = sr[j], q1 = si[j];
            sr[i] = c * r0 + s * q1;  si[i] = c * q0 - s * r1;
            sr[j] = c * r1 + s * q0;  si[j] = c * q1 - s * r0;
        }
    }
}

__global__ __launch_bounds__(256) void qcnn_fused_kernel(
        const float* __restrict__ x, const float* __restrict__ qw,
        const float* __restrict__ fc_w, const float* __restrict__ fc_b,
        float* __restrict__ out) {
    __shared__ float feats[NFEAT];

    const int b = blockIdx.x;
    const int t = threadIdx.x;

    if (t < NPAT) {
        // ---- patch pixel fetch ----
        const int pr = t / NPSD, pc = t % NPSD;
        const float* img = x + (size_t)b * (IMGS * IMGS);
        const float* p0 = img + (2 * pr) * IMGS + 2 * pc;
        const float a0 = p0[0], a1 = p0[1], a2 = p0[IMGS], a3 = p0[IMGS + 1];

        // ---- data encoding: product state of RY(a*pi) on |0> per qubit ----
        float ce[4], se[4];
        const float HPI = 1.57079632679489662f;  // pi/2 (half of angle a*pi)
        sincosf(a0 * HPI, &se[0], &ce[0]);
        sincosf(a1 * HPI, &se[1], &ce[1]);
        sincosf(a2 * HPI, &se[2], &ce[2]);
        sincosf(a3 * HPI, &se[3], &ce[3]);

        float sr[16], si[16];
#pragma unroll
        for (int i = 0; i < 16; ++i) {
            float v = ((i & 8) ? se[0] : ce[0]) * ((i & 4) ? se[1] : ce[1]) *
                      ((i & 2) ? se[2] : ce[2]) * ((i & 1) ? se[3] : ce[3]);
            sr[i] = v;
            si[i] = 0.0f;
        }

        // ---- circuit weights (broadcast loads, cached) ----
        float cw[12], sw[12];
#pragma unroll
        for (int i = 0; i < 12; ++i) sincosf(qw[i] * 0.5f, &sw[i], &cw[i]);

        // qubit q <-> mask (8 >> q)
        // conv1
        ry_gate<8>(sr, si, cw[0], sw[0]);   // RY q0
        ry_gate<4>(sr, si, cw[1], sw[1]);   // RY q1
        cx_gate<8, 4>(sr, si);              // CX 0->1
        ry_gate<2>(sr, si, cw[2], sw[2]);   // RY q2
        ry_gate<1>(sr, si, cw[3], sw[3]);   // RY q3
        cx_gate<2, 1>(sr, si);              // CX 2->3
        cx_gate<4, 2>(sr, si);              // CX 1->2
        cx_gate<1, 8>(sr, si);              // CX 3->0
        // pool1
        crx_gate<4, 8>(sr, si, cw[4], sw[4]);   // CRX c=1 t=0
        crx_gate<1, 2>(sr, si, cw[5], sw[5]);   // CRX c=3 t=2
        // conv2
        ry_gate<8>(sr, si, cw[6], sw[6]);   // RY q0
        ry_gate<2>(sr, si, cw[7], sw[7]);   // RY q2
        cx_gate<8, 2>(sr, si);              // CX 0->2
        ry_gate<8>(sr, si, cw[8], sw[8]);   // RY q0
        ry_gate<2>(sr, si, cw[9], sw[9]);   // RY q2
        // pool2
        crx_gate<2, 8>(sr, si, cw[10], sw[10]); // CRX c=2 t=0
        ry_gate<8>(sr, si, cw[11], sw[11]);     // RY q0

        // ---- Bloch vector of qubit 0 ----
        float ex = 0.f, ey = 0.f, ez = 0.f;
#pragma unroll
        for (int j = 0; j < 8; ++j) {
            float r0 = sr[j], q0 = si[j], r1 = sr[j + 8], q1 = si[j + 8];
            ex += r0 * r1 + q0 * q1;
            ey += r0 * q1 - q0 * r1;
            ez += (r0 * r0 + q0 * q0) - (r1 * r1 + q1 * q1);
        }
        feats[t * 3 + 0] = 2.0f * ex;
        feats[t * 3 + 1] = 2.0f * ey;
        feats[t * 3 + 2] = ez;
    }

    __syncthreads();

    // ---- FC: 10 classes x 16 lanes each ----
    if (t < NCLS * 16) {
        const int c = t >> 4, l = t & 15;
        const float* w = fc_w + c * NFEAT;
        float acc = 0.0f;
        for (int j = l; j < NFEAT; j += 16) acc += feats[j] * w[j];
#pragma unroll
        for (int off = 8; off >= 1; off >>= 1) acc += __shfl_xor(acc, off, 64);
        if (l == 0) out[b * NCLS + c] = acc + fc_b[c];
    }
}

extern "C" void kernel_launch(void* const* d_in, const int* in_sizes, int n_in,
                              void* d_out, int out_size, void* d_ws, size_t ws_size,
                              hipStream_t stream) {
    const float* x    = (const float*)d_in[0];
    const float* qw   = (const float*)d_in[1];
    const float* fc_w = (const float*)d_in[2];
    const float* fc_b = (const float*)d_in[3];
    float* out = (float*)d_out;

    const int B = in_sizes[0] / (IMGS * IMGS);
    qcnn_fused_kernel<<<B, 256, 0, stream>>>(x, qw, fc_w, fc_b, out);
}

// Round 2
// 12.565 us; speedup vs baseline: 1.1558x; 1.1558x over previous
//
#include <hip/hip_runtime.h>
#include <math.h>

#define IMGS 28
#define NPSD 14
#define NPAT 196
#define NCLS 10
#define NFEAT (NPAT * 3)

// Fast native trig: v_sin_f32 / v_cos_f32 (args here are all in [-pi/2, pi/2],
// where the native ops are ~1e-6 accurate; absmax threshold is 1e-2).
__device__ __forceinline__ void fsincos(float x, float& s, float& c) {
    s = __sinf(x);
    c = __cosf(x);
}

// ---- 4-qubit gate helpers: all indices compile-time (templates + unroll) ----

template <int MASK>
__device__ __forceinline__ void ry_gate(float (&sr)[16], float (&si)[16], float c, float s) {
#pragma unroll
    for (int i = 0; i < 16; ++i) {
        if (i & MASK) continue;
        const int j = i | MASK;
        float r0 = sr[i], q0 = si[i], r1 = sr[j], q1 = si[j];
        sr[i] = c * r0 - s * r1;  si[i] = c * q0 - s * q1;
        sr[j] = s * r0 + c * r1;  si[j] = s * q0 + c * q1;
    }
}

template <int MC, int MT>
__device__ __forceinline__ void cx_gate(float (&sr)[16], float (&si)[16]) {
#pragma unroll
    for (int i = 0; i < 16; ++i) {
        if ((i & MC) && !(i & MT)) {
            const int j = i | MT;
            float tr = sr[i], ti = si[i];
            sr[i] = sr[j]; si[i] = si[j];
            sr[j] = tr;    si[j] = ti;
        }
    }
}

template <int MC, int MT>
__device__ __forceinline__ void crx_gate(float (&sr)[16], float (&si)[16], float c, float s) {
#pragma unroll
    for (int i = 0; i < 16; ++i) {
        if ((i & MC) && !(i & MT)) {
            const int j = i | MT;
            float r0 = sr[i], q0 = si[i], r1 = sr[j], q1 = si[j];
            sr[i] = c * r0 + s * q1;  si[i] = c * q0 - s * r1;
            sr[j] = c * r1 + s * q0;  si[j] = c * q1 - s * r0;
        }
    }
}

__global__ __launch_bounds__(256) void qcnn_fused_kernel(
        const float* __restrict__ x, const float* __restrict__ qw,
        const float* __restrict__ fc_w, const float* __restrict__ fc_b,
        float* __restrict__ out) {
    __shared__ float feats[NFEAT];

    const int b = blockIdx.x;
    const int t = threadIdx.x;

    if (t < NPAT) {
        // ---- patch pixel fetch ----
        const int pr = t / NPSD, pc = t % NPSD;
        const float* img = x + (size_t)b * (IMGS * IMGS);
        const float* p0 = img + (2 * pr) * IMGS + 2 * pc;
        const float a0 = p0[0], a1 = p0[1], a2 = p0[IMGS], a3 = p0[IMGS + 1];

        // ---- data encoding: product state of RY(a*pi) on |0> per qubit ----
        float ce[4], se[4];
        const float HPI = 1.57079632679489662f;  // pi/2 (half of angle a*pi)
        fsincos(a0 * HPI, se[0], ce[0]);
        fsincos(a1 * HPI, se[1], ce[1]);
        fsincos(a2 * HPI, se[2], ce[2]);
        fsincos(a3 * HPI, se[3], ce[3]);

        float sr[16], si[16];
#pragma unroll
        for (int i = 0; i < 16; ++i) {
            float v = ((i & 8) ? se[0] : ce[0]) * ((i & 4) ? se[1] : ce[1]) *
                      ((i & 2) ? se[2] : ce[2]) * ((i & 1) ? se[3] : ce[3]);
            sr[i] = v;
            si[i] = 0.0f;
        }

        // ---- circuit weights (broadcast loads, cached) ----
        float cw[12], sw[12];
#pragma unroll
        for (int i = 0; i < 12; ++i) fsincos(qw[i] * 0.5f, sw[i], cw[i]);

        // qubit q <-> mask (8 >> q)
        // conv1
        ry_gate<8>(sr, si, cw[0], sw[0]);   // RY q0
        ry_gate<4>(sr, si, cw[1], sw[1]);   // RY q1
        cx_gate<8, 4>(sr, si);              // CX 0->1
        ry_gate<2>(sr, si, cw[2], sw[2]);   // RY q2
        ry_gate<1>(sr, si, cw[3], sw[3]);   // RY q3
        cx_gate<2, 1>(sr, si);              // CX 2->3
        cx_gate<4, 2>(sr, si);              // CX 1->2
        cx_gate<1, 8>(sr, si);              // CX 3->0
        // pool1
        crx_gate<4, 8>(sr, si, cw[4], sw[4]);   // CRX c=1 t=0
        crx_gate<1, 2>(sr, si, cw[5], sw[5]);   // CRX c=3 t=2
        // conv2
        ry_gate<8>(sr, si, cw[6], sw[6]);   // RY q0
        ry_gate<2>(sr, si, cw[7], sw[7]);   // RY q2
        cx_gate<8, 2>(sr, si);              // CX 0->2
        ry_gate<8>(sr, si, cw[8], sw[8]);   // RY q0
        ry_gate<2>(sr, si, cw[9], sw[9]);   // RY q2
        // pool2
        crx_gate<2, 8>(sr, si, cw[10], sw[10]); // CRX c=2 t=0
        ry_gate<8>(sr, si, cw[11], sw[11]);     // RY q0

        // ---- Bloch vector of qubit 0 ----
        float ex = 0.f, ey = 0.f, ez = 0.f;
#pragma unroll
        for (int j = 0; j < 8; ++j) {
            float r0 = sr[j], q0 = si[j], r1 = sr[j + 8], q1 = si[j + 8];
            ex += r0 * r1 + q0 * q1;
            ey += r0 * q1 - q0 * r1;
            ez += (r0 * r0 + q0 * q0) - (r1 * r1 + q1 * q1);
        }
        feats[t * 3 + 0] = 2.0f * ex;
        feats[t * 3 + 1] = 2.0f * ey;
        feats[t * 3 + 2] = ez;
    }

    __syncthreads();

    // ---- FC: 10 classes x 16 lanes each ----
    if (t < NCLS * 16) {
        const int c = t >> 4, l = t & 15;
        const float* w = fc_w + c * NFEAT;
        float acc = 0.0f;
        for (int j = l; j < NFEAT; j += 16) acc += feats[j] * w[j];
#pragma unroll
        for (int off = 8; off >= 1; off >>= 1) acc += __shfl_xor(acc, off, 64);
        if (l == 0) out[b * NCLS + c] = acc + fc_b[c];
    }
}

extern "C" void kernel_launch(void* const* d_in, const int* in_sizes, int n_in,
                              void* d_out, int out_size, void* d_ws, size_t ws_size,
                              hipStream_t stream) {
    const float* x    = (const float*)d_in[0];
    const float* qw   = (const float*)d_in[1];
    const float* fc_w = (const float*)d_in[2];
    const float* fc_b = (const float*)d_in[3];
    float* out = (float*)d_out;

    const int B = in_sizes[0] / (IMGS * IMGS);
    qcnn_fused_kernel<<<B, 256, 0, stream>>>(x, qw, fc_w, fc_b, out);
}

// Round 3
// 10.161 us; speedup vs baseline: 1.4292x; 1.2366x over previous
//
#include <hip/hip_runtime.h>
#include <math.h>

#define IMGS 28
#define NPSD 14
#define NPAT 196
#define NCLS 10
#define NFEAT (NPAT * 3)

// Fast native trig: args all in [-pi/2, pi/2]; ~1e-6 error vs 1e-2 threshold.
__device__ __forceinline__ void fsincos(float x, float& s, float& c) {
    s = __sinf(x);
    c = __cosf(x);
}

// ---- 4-qubit gate helpers: all indices compile-time (templates + unroll) ----

template <int MASK>
__device__ __forceinline__ void ry_gate(float (&sr)[16], float (&si)[16], float c, float s) {
#pragma unroll
    for (int i = 0; i < 16; ++i) {
        if (i & MASK) continue;
        const int j = i | MASK;
        float r0 = sr[i], q0 = si[i], r1 = sr[j], q1 = si[j];
        sr[i] = c * r0 - s * r1;  si[i] = c * q0 - s * q1;
        sr[j] = s * r0 + c * r1;  si[j] = s * q0 + c * q1;
    }
}

template <int MC, int MT>
__device__ __forceinline__ void cx_gate(float (&sr)[16], float (&si)[16]) {
#pragma unroll
    for (int i = 0; i < 16; ++i) {
        if ((i & MC) && !(i & MT)) {
            const int j = i | MT;
            float tr = sr[i], ti = si[i];
            sr[i] = sr[j]; si[i] = si[j];
            sr[j] = tr;    si[j] = ti;
        }
    }
}

template <int MC, int MT>
__device__ __forceinline__ void crx_gate(float (&sr)[16], float (&si)[16], float c, float s) {
#pragma unroll
    for (int i = 0; i < 16; ++i) {
        if ((i & MC) && !(i & MT)) {
            const int j = i | MT;
            float r0 = sr[i], q0 = si[i], r1 = sr[j], q1 = si[j];
            sr[i] = c * r0 + s * q1;  si[i] = c * q0 - s * r1;
            sr[j] = c * r1 + s * q0;  si[j] = c * q1 - s * r0;
        }
    }
}

__global__ __launch_bounds__(256) void qcnn_fused_kernel(
        const float* __restrict__ x, const float* __restrict__ qw,
        const float* __restrict__ fc_w, const float* __restrict__ fc_b,
        float* __restrict__ out) {
    __shared__ float partial[4][NCLS];

    const int b = blockIdx.x;
    const int t = threadIdx.x;

    float con[NCLS];
#pragma unroll
    for (int c = 0; c < NCLS; ++c) con[c] = 0.0f;

    if (t < NPAT) {
        // ---- patch pixel fetch ----
        const int pr = t / NPSD, pc = t % NPSD;
        const float* img = x + (size_t)b * (IMGS * IMGS);
        const float* p0 = img + (2 * pr) * IMGS + 2 * pc;
        const float a0 = p0[0], a1 = p0[1], a2 = p0[IMGS], a3 = p0[IMGS + 1];

        // ---- data encoding: product state of RY(a*pi) on |0> per qubit ----
        float ce[4], se[4];
        const float HPI = 1.57079632679489662f;  // pi/2 (half of angle a*pi)
        fsincos(a0 * HPI, se[0], ce[0]);
        fsincos(a1 * HPI, se[1], ce[1]);
        fsincos(a2 * HPI, se[2], ce[2]);
        fsincos(a3 * HPI, se[3], ce[3]);

        float sr[16], si[16];
#pragma unroll
        for (int i = 0; i < 16; ++i) {
            float v = ((i & 8) ? se[0] : ce[0]) * ((i & 4) ? se[1] : ce[1]) *
                      ((i & 2) ? se[2] : ce[2]) * ((i & 1) ? se[3] : ce[3]);
            sr[i] = v;
            si[i] = 0.0f;
        }

        // ---- circuit weights (broadcast loads, cached) ----
        float cw[12], sw[12];
#pragma unroll
        for (int i = 0; i < 12; ++i) fsincos(qw[i] * 0.5f, sw[i], cw[i]);

        // qubit q <-> mask (8 >> q)
        // conv1
        ry_gate<8>(sr, si, cw[0], sw[0]);
        ry_gate<4>(sr, si, cw[1], sw[1]);
        cx_gate<8, 4>(sr, si);
        ry_gate<2>(sr, si, cw[2], sw[2]);
        ry_gate<1>(sr, si, cw[3], sw[3]);
        cx_gate<2, 1>(sr, si);
        cx_gate<4, 2>(sr, si);
        cx_gate<1, 8>(sr, si);
        // pool1
        crx_gate<4, 8>(sr, si, cw[4], sw[4]);
        crx_gate<1, 2>(sr, si, cw[5], sw[5]);
        // conv2
        ry_gate<8>(sr, si, cw[6], sw[6]);
        ry_gate<2>(sr, si, cw[7], sw[7]);
        cx_gate<8, 2>(sr, si);
        ry_gate<8>(sr, si, cw[8], sw[8]);
        ry_gate<2>(sr, si, cw[9], sw[9]);
        // pool2
        crx_gate<2, 8>(sr, si, cw[10], sw[10]);
        ry_gate<8>(sr, si, cw[11], sw[11]);

        // ---- Bloch vector of qubit 0 ----
        float ex = 0.f, ey = 0.f, ez = 0.f;
#pragma unroll
        for (int j = 0; j < 8; ++j) {
            float r0 = sr[j], q0 = si[j], r1 = sr[j + 8], q1 = si[j + 8];
            ex += r0 * r1 + q0 * q1;
            ey += r0 * q1 - q0 * r1;
            ez += (r0 * r0 + q0 * q0) - (r1 * r1 + q1 * q1);
        }
        ex *= 2.0f;
        ey *= 2.0f;

        // ---- fold features into per-class contributions (coalesced w loads) ----
#pragma unroll
        for (int c = 0; c < NCLS; ++c) {
            const float* w = fc_w + c * NFEAT + 3 * t;
            con[c] = ex * w[0] + ey * w[1] + ez * w[2];
        }
    }

    // ---- 64-lane butterfly reduce per class ----
#pragma unroll
    for (int c = 0; c < NCLS; ++c) {
        float v = con[c];
#pragma unroll
        for (int off = 32; off >= 1; off >>= 1) v += __shfl_xor(v, off, 64);
        con[c] = v;
    }

    const int wave = t >> 6, lane = t & 63;
    if (lane == 0) {
#pragma unroll
        for (int c = 0; c < NCLS; ++c) partial[wave][c] = con[c];
    }
    __syncthreads();

    if (t < NCLS) {
        out[b * NCLS + t] = partial[0][t] + partial[1][t] + partial[2][t] +
                            partial[3][t] + fc_b[t];
    }
}

extern "C" void kernel_launch(void* const* d_in, const int* in_sizes, int n_in,
                              void* d_out, int out_size, void* d_ws, size_t ws_size,
                              hipStream_t stream) {
    const float* x    = (const float*)d_in[0];
    const float* qw   = (const float*)d_in[1];
    const float* fc_w = (const float*)d_in[2];
    const float* fc_b = (const float*)d_in[3];
    float* out = (float*)d_out;

    const int B = in_sizes[0] / (IMGS * IMGS);
    qcnn_fused_kernel<<<B, 256, 0, stream>>>(x, qw, fc_w, fc_b, out);
}